// Round 17
// baseline (281.689 us; speedup 1.0000x reference)
//
#include <hip/hip_runtime.h>
#include <hip/hip_bf16.h>
#include <stdint.h>

// MutualCrossAttention: B=8, C=64, H=W=64 -> T=4096 tokens. Inputs FP32, output FP32.
// dir A: Q=x1, K=V=x2 ; dir B: Q=x2, K=V=x1 ; out = outA + outB, layout [b][c][t].
// R29: L1-BANDWIDTH attack. Cycle audit of R25/R28 (104.5us, 7.8k cyc/j-pair vs
// ~1.5k compute): the dominant unmodeled term is the vector-L1 port. Every wave
// loaded private K+V (16KB/j) and pair-waves loaded IDENTICAL tiles -> issued
// L1 traffic 256KB/CU/j-pair ~ 4k cyc @64B/cyc; grid-wide 2GB ~ 53us. Fix:
// each wave now covers ALL 64 q-rows (rb=0..3) of its qt; waves = (ksq 0..3,
// dir) -> every (dir, token-quarter) tile is loaded EXACTLY ONCE per block.
// L1 traffic halves (1GB); MFMA total unchanged (64/j/wave x 16 j x 8 waves).
// Carried from R25/R28 (proven): frag-packed K/V/Q layout (1KB/instr loads),
// parity pbuf (S(j+1) and PV(j) in different DS regions), barrier-free
// counted-vmcnt loop, named single K/V prefetch sets, no-launch-bounds
// allocation (R24: allocator sizes to demand ~190 < 256, no spill).
//   kt chunk(tt,mt,ch):  lane(quad,l16) holds K[t=tt*64+mt*16+l16][c=ch*32+quad*8+e]
//   vt chunk(tt,ch2,ct): lane(quad,l16) holds V[c=ct*16+l16][t=tt*64+ch2*32+quad*8+e]
// Q frags: qf[rb][ch] = kt chunk (qt, mt=rb, ch) — q row = rb*16+l16.
// Per j (64-token tile of the wave's quarter): S^T: 4mt x 4rb x 2 = 32 MFMA ->
// exp2 -> pack -> b64 pbuf write; PV: 2ch2 x 4ct x 4rb = 32 MFMA from b128
// pbuf reads + V frags. accO[rb][ct] = O^T [c=ct*16+quad*4+r][q=rb*16+l16].
// Epilogue: lp butterflied over quads; cross-wave denominator = sum of lpx over
// the 4 same-dir waves; 8-phase xbuf merge (all waves' normalized partials add;
// per-dir inv is correct since out = outA+outB each separately normalized).
// LDS: pbuf[8][2][4][16][72] = 144KB + lpx 2KB = 146KB <= 160 (1 blk/CU anyway).
// ws: [0,8MB) kt bf16 frag-packed {x1,x2} PRE-SCALED by sqrt(log2(e)/8);
//     [8MB,16MB) vt bf16 frag-packed {x1,x2} unscaled.

#define TT 4096
#define CC 64
#define NB 8

typedef float f32x4 __attribute__((ext_vector_type(4)));
typedef float f32x4a __attribute__((ext_vector_type(4), may_alias));
typedef short s16x8 __attribute__((ext_vector_type(8)));
typedef unsigned int u32x2a __attribute__((ext_vector_type(2), may_alias));
typedef unsigned int u32x4a __attribute__((ext_vector_type(4), may_alias));
typedef float f32a __attribute__((may_alias));

static __device__ __forceinline__ unsigned fbits(float x) { return __float_as_uint(x); }
static __device__ __forceinline__ ushort bf16of(float v) {
    return (ushort)((fbits(v) + 0x8000u) >> 16);
}
static __device__ __forceinline__ unsigned pack2(float a, float b) {
    return __builtin_amdgcn_perm(fbits(b) + 0x8000u, fbits(a) + 0x8000u, 0x07060302u);
}
static __device__ __forceinline__ s16x8 load_frag(const void* p) {
    u32x4a t = *(const u32x4a*)p;
    return __builtin_bit_cast(s16x8, t);
}

#define SQC1 0.4246609177f  // sqrt(log2(e)/8), applied to kt on both Q and K sides

// grid (TT/64, NB, 2), 256 threads. Reads c-major f32, emits frag-packed bf16.
__global__ void prep_k(const float* __restrict__ x1, const float* __restrict__ x2,
                       ushort* __restrict__ kt, ushort* __restrict__ vt) {
    const int inp = blockIdx.z, b = blockIdx.y, tt = blockIdx.x;
    const float* src = (inp == 0 ? x1 : x2) + (size_t)b * CC * TT;
    const size_t plane = (size_t)TT * CC;
    ushort* kd = kt + (size_t)(inp * NB + b) * plane;
    ushort* vd = vt + (size_t)(inp * NB + b) * plane;
    __shared__ ushort lds[64][72];
    const int tid = threadIdx.x;
    const int c  = tid >> 2;        // 0..63: channel row
    const int tg = tid & 3;         // 16-token group within the 64-token tile
    const float* srow = src + (size_t)c * TT + tt * 64 + tg * 16;
    unsigned hw[8];
#pragma unroll
    for (int i = 0; i < 4; ++i) {
        f32x4a v = *(const f32x4a*)(srow + i * 4);
        hw[2 * i]     = pack2(v[0], v[1]);
        hw[2 * i + 1] = pack2(v[2], v[3]);
#pragma unroll
        for (int k = 0; k < 4; ++k) lds[tg * 16 + i * 4 + k][c] = bf16of(v[k] * SQC1);
    }
    // vt frag-packed (unscaled): thread(c,tg) owns V[c][t_local=tg*16..+16] =
    // chunk(tt, ch2=tg>>1, ct=c>>4), lanes (quad=(tg&1)*2 and +1, l16=c&15).
    {
        ushort* vchunk = vd + (((size_t)tt * 2 + (tg >> 1)) * 4 + (c >> 4)) * 512;
        const int l16v = c & 15;
        const int q0v  = (tg & 1) * 2;
        u32x4a w0 = {hw[0], hw[1], hw[2], hw[3]};
        u32x4a w1 = {hw[4], hw[5], hw[6], hw[7]};
        *(u32x4a*)(vchunk + (size_t)(q0v * 16 + l16v) * 8)       = w0;
        *(u32x4a*)(vchunk + (size_t)((q0v + 1) * 16 + l16v) * 8) = w1;
    }
    __syncthreads();
    // kt frag-packed (scaled, from transposed LDS): tid = mt*64 + quad*16 + l16.
    // chunk(tt, mt, ch): lane holds 8 consecutive c at row t = mt*16 + l16.
    const int mt   = tid >> 6;
    const int quad = (tid >> 4) & 3;
    const int l16  = tid & 15;
    const int t    = mt * 16 + l16;
#pragma unroll
    for (int ch = 0; ch < 2; ++ch) {
        u32x4a w = *(const u32x4a*)&lds[t][ch * 32 + quad * 8];
        *(u32x4a*)(kd + (((size_t)tt * 4 + mt) * 2 + ch) * 512 +
                   (size_t)(quad * 16 + l16) * 8) = w;
    }
}

// grid = 512 blocks (qt 0..63 x b 0..7), 512 threads = 8 waves.
// wave: dir = w&1, ksq = w>>1 (1024-token quarter); each wave does all 64 q.
__global__ __attribute__((amdgpu_flat_work_group_size(512, 512)))
void attn_fused_k(const ushort* __restrict__ kt, const ushort* __restrict__ vt,
                  float* __restrict__ out) {
    const int b    = blockIdx.x & 7;
    const int qt   = blockIdx.x >> 3;
    const int tid  = threadIdx.x;
    const int wave = tid >> 6;
    const int lane = tid & 63;
    const int quad = lane >> 4;
    const int l16  = lane & 15;
    const int dir  = wave & 1;
    const int ksq  = wave >> 1;      // 0..3: token quarter, 16 j-tiles each

    const size_t plane = (size_t)TT * CC;
    // All hot-loop loads: base + chunk*512 + lane*8 (ushorts) = contiguous 1KB/instr.
    const ushort* Qp = kt + (size_t)((dir == 0 ? 0 : NB) + b) * plane + (size_t)lane * 8;
    const ushort* Kp = kt + (size_t)((dir == 0 ? NB : 0) + b) * plane + (size_t)lane * 8;
    const ushort* Vp = vt + (size_t)((dir == 0 ? NB : 0) + b) * plane + (size_t)lane * 8;

    // Parity pbuf: S(j+1) writes and PV(j) reads touch different regions.
    __shared__ __align__(16) ushort pbuf[8][2][4][16][72];  // 144 KB
    __shared__ float lpx[8][4][16];                         // 2 KB
    f32a* xbuf = (f32a*)&pbuf[0][0][0][0][0];               // 16 KB overlay, post-loop

    // Q b-frags: qf[rb][ch] = kt chunk (qt, mt=rb, ch); q row = rb*16+l16.
    s16x8 qf[4][2];
#pragma unroll
    for (int rb = 0; rb < 4; ++rb)
#pragma unroll
        for (int ch = 0; ch < 2; ++ch)
            qf[rb][ch] = load_frag(Qp + (((size_t)qt * 4 + rb) * 2 + ch) * 512);

    f32x4 accO[4][4];  // O^T partial: row=c=ct*16+quad*4+r, col=q=rb*16+l16
#pragma unroll
    for (int rb = 0; rb < 4; ++rb)
#pragma unroll
        for (int ct = 0; ct < 4; ++ct) accO[rb][ct] = (f32x4){0.f, 0.f, 0.f, 0.f};
    float lp[4] = {0.f, 0.f, 0.f, 0.f};

    // SINGLE named K set + V set (arrays spill — R14/R15).
    s16x8 k0, k1, k2, k3, k4, k5, k6, k7;
    s16x8 v0, v1, v2, v3, v4, v5, v6, v7;

    auto loadK = [&](int j) {
        const ushort* p = Kp + (size_t)(ksq * 16 + j) * 4096;
        k0 = load_frag(p);          k1 = load_frag(p + 512);
        k2 = load_frag(p + 1024);   k3 = load_frag(p + 1536);
        k4 = load_frag(p + 2048);   k5 = load_frag(p + 2560);
        k6 = load_frag(p + 3072);   k7 = load_frag(p + 3584);
    };
    auto loadV = [&](int j) {
        const ushort* p = Vp + (size_t)(ksq * 16 + j) * 4096;
        v0 = load_frag(p);          v1 = load_frag(p + 512);
        v2 = load_frag(p + 1024);   v3 = load_frag(p + 1536);
        v4 = load_frag(p + 2048);   v5 = load_frag(p + 2560);
        v6 = load_frag(p + 3072);   v7 = load_frag(p + 3584);
    };

    // One mt-slice of S^T into parity region par, all 4 rb:
    // D[row=tok=quad*4+r (+mt*16)][col=q=rb*16+l16] -> b64 P write.
    auto SmT = [&](s16x8 kc0, s16x8 kc1, int mt, int par) {
#pragma unroll
        for (int rb = 0; rb < 4; ++rb) {
            f32x4 s = (f32x4){0.f, 0.f, 0.f, 0.f};
            s = __builtin_amdgcn_mfma_f32_16x16x32_bf16(kc0, qf[rb][0], s, 0, 0, 0);
            s = __builtin_amdgcn_mfma_f32_16x16x32_bf16(kc1, qf[rb][1], s, 0, 0, 0);
            float p0 = __builtin_amdgcn_exp2f(s[0]);
            float p1 = __builtin_amdgcn_exp2f(s[1]);
            float p2 = __builtin_amdgcn_exp2f(s[2]);
            float p3 = __builtin_amdgcn_exp2f(s[3]);
            lp[rb] += (p0 + p1) + (p2 + p3);
            u32x2a w;
            w[0] = pack2(p0, p1);
            w[1] = pack2(p2, p3);
            *(u32x2a*)&pbuf[wave][par][rb][l16][mt * 16 + quad * 4] = w;
        }
    };
    auto Sphase = [&](int par) {
        SmT(k0, k1, 0, par); SmT(k2, k3, 1, par);
        SmT(k4, k5, 2, par); SmT(k6, k7, 3, par);
    };

    // PV from parity region par with the V set: 2ch2 x 4ct x 4rb MFMA.
    auto PVphase = [&](int par) {
        s16x8 pfa[4], pfb[4];
#pragma unroll
        for (int rb = 0; rb < 4; ++rb)
            pfa[rb] = load_frag(&pbuf[wave][par][rb][l16][quad * 8]);
#pragma unroll
        for (int rb = 0; rb < 4; ++rb) {
            accO[rb][0] = __builtin_amdgcn_mfma_f32_16x16x32_bf16(v0, pfa[rb], accO[rb][0], 0, 0, 0);
            accO[rb][1] = __builtin_amdgcn_mfma_f32_16x16x32_bf16(v1, pfa[rb], accO[rb][1], 0, 0, 0);
            accO[rb][2] = __builtin_amdgcn_mfma_f32_16x16x32_bf16(v2, pfa[rb], accO[rb][2], 0, 0, 0);
            accO[rb][3] = __builtin_amdgcn_mfma_f32_16x16x32_bf16(v3, pfa[rb], accO[rb][3], 0, 0, 0);
        }
#pragma unroll
        for (int rb = 0; rb < 4; ++rb)
            pfb[rb] = load_frag(&pbuf[wave][par][rb][l16][32 + quad * 8]);
#pragma unroll
        for (int rb = 0; rb < 4; ++rb) {
            accO[rb][0] = __builtin_amdgcn_mfma_f32_16x16x32_bf16(v4, pfb[rb], accO[rb][0], 0, 0, 0);
            accO[rb][1] = __builtin_amdgcn_mfma_f32_16x16x32_bf16(v5, pfb[rb], accO[rb][1], 0, 0, 0);
            accO[rb][2] = __builtin_amdgcn_mfma_f32_16x16x32_bf16(v6, pfb[rb], accO[rb][2], 0, 0, 0);
            accO[rb][3] = __builtin_amdgcn_mfma_f32_16x16x32_bf16(v7, pfb[rb], accO[rb][3], 0, 0, 0);
        }
    };

    // Barrier-free parity pipeline over the wave's 16 tiles, unroll 2.
    // Per iter (j even):
    //   S(j)->par0 | loadK(j+1) | PV(j-1)<-par1 | loadV(j) |
    //   S(j+1)->par1 | loadK(j+2) | PV(j)<-par0 | loadV(j+1)
    // vmcnt queue after loadV(j): [K(j+1), V(j)] -> S(j+1) waits vmcnt(8);
    // after loadK(j+2): [V(j), K(j+2)] -> PV(j) waits vmcnt(8). Counted waits
    // throughout; every load has >=1 sub-phase of cover.
    loadK(0);
#pragma unroll 1
    for (int j = 0; j < 16; j += 2) {
        Sphase(0);                       // S(j), uses K(j)
        loadK(j + 1);
        if (j > 0) PVphase(1);           // PV(j-1), uses V(j-1)
        loadV(j);
        Sphase(1);                       // S(j+1), uses K(j+1)
        if (j + 2 < 16) loadK(j + 2);
        PVphase(0);                      // PV(j), uses V(j)
        loadV(j + 1);
    }
    PVphase(1);                          // PV(15)

    // Denominator: quads hold disjoint token subsets for col q; butterfly, then
    // sum over the 4 same-dir waves (ksq quarters) via lpx.
#pragma unroll
    for (int rb = 0; rb < 4; ++rb) {
        float l = lp[rb];
        l += __shfl_xor(l, 16);
        l += __shfl_xor(l, 32);
        lp[rb] = l;
        if (lane < 16) lpx[wave][rb][l16] = l;
    }
    __syncthreads();  // joins ALL waves after their last pbuf use ->
                      // xbuf overlay safe; lpx visible
    float inv[4];
#pragma unroll
    for (int rb = 0; rb < 4; ++rb) {
        float l = lpx[dir][rb][l16] + lpx[2 + dir][rb][l16] +
                  lpx[4 + dir][rb][l16] + lpx[6 + dir][rb][l16];
        inv[rb] = __builtin_amdgcn_rcpf(l);
    }

    // 8-phase merge over waves into xbuf (all partials normalized per-dir,
    // outA+outB sum falls out naturally); wave 0 stores.
#pragma unroll 1
    for (int ph = 7; ph >= 1; --ph) {
        if (wave == ph) {
#pragma unroll
            for (int rb = 0; rb < 4; ++rb)
#pragma unroll
                for (int ct = 0; ct < 4; ++ct)
#pragma unroll
                    for (int r = 0; r < 4; ++r) {
                        const int slot = (rb * 16 + ct * 4 + r) * 64 + lane;
                        float v = accO[rb][ct][r] * inv[rb];
                        if (ph == 7) xbuf[slot] = v;
                        else xbuf[slot] += v;
                    }
        }
        __syncthreads();
    }
    if (wave == 0) {
        float* ob = out + (size_t)b * plane;
#pragma unroll
        for (int rb = 0; rb < 4; ++rb)
#pragma unroll
            for (int ct = 0; ct < 4; ++ct)
#pragma unroll
                for (int r = 0; r < 4; ++r) {
                    float v = accO[rb][ct][r] * inv[rb] +
                              xbuf[(rb * 16 + ct * 4 + r) * 64 + lane];
                    // out[c = ct*16+quad*4+r][t = qt*64 + rb*16 + l16]
                    ob[(size_t)(ct * 16 + quad * 4 + r) * TT + qt * 64 + rb * 16 + l16] = v;
                }
    }
}

extern "C" void kernel_launch(void* const* d_in, const int* in_sizes, int n_in,
                              void* d_out, int out_size, void* d_ws, size_t ws_size,
                              hipStream_t stream) {
    const float* x1 = (const float*)d_in[0];
    const float* x2 = (const float*)d_in[1];
    ushort* kt = (ushort*)d_ws;                              // 8 MB frag-packed K/Q
    ushort* vt = (ushort*)d_ws + (size_t)2 * NB * TT * CC;   // 8 MB frag-packed V

    hipLaunchKernelGGL(prep_k, dim3(TT / 64, NB, 2), dim3(256), 0, stream, x1, x2, kt, vt);
    hipLaunchKernelGGL(attn_fused_k, dim3(64 * NB), dim3(512), 0, stream,
                       kt, vt, (float*)d_out);
}

// Round 18
// 281.607 us; speedup vs baseline: 1.0003x; 1.0003x over previous
//
#include <hip/hip_runtime.h>
#include <hip/hip_bf16.h>
#include <stdint.h>

// MutualCrossAttention: B=8, C=64, H=W=64 -> T=4096 tokens. Inputs FP32, output FP32.
// dir A: Q=x1, K=V=x2 ; dir B: Q=x2, K=V=x1 ; out = outA + outB, layout [b][c][t].
// R30 = R29 + __launch_bounds__(512, 1). R29's L1-dedup restructure (each wave
// covers ALL 64 q-rows of its qt; waves = (ksq quarter, dir) -> every K/V tile
// loaded ONCE per block, L1 traffic 2GB -> 1GB) never got tested: the
// no-launch-bounds allocator caps 512-thr kernels at 128 VGPR by default
// (R24's "sizes to demand" only held because demand 112 < 128), and R29's
// ~190-reg demand spilled (WRITE 430MB, 230us). R28 proved (512,1) raises the
// cap to 256 with ZERO residency cost (occupancy unchanged at 20.5%). This is
// the one-line fix, same pattern as R15->R16 (which recovered 4.3x).
// Carried from R25/R28 (proven): frag-packed K/V/Q layout (1KB/instr loads),
// parity pbuf (S(j+1) and PV(j) in different DS regions), barrier-free
// counted-vmcnt loop, named single K/V prefetch sets.
//   kt chunk(tt,mt,ch):  lane(quad,l16) holds K[t=tt*64+mt*16+l16][c=ch*32+quad*8+e]
//   vt chunk(tt,ch2,ct): lane(quad,l16) holds V[c=ct*16+l16][t=tt*64+ch2*32+quad*8+e]
// Q frags: qf[rb][ch] = kt chunk (qt, mt=rb, ch) — q row = rb*16+l16.
// Per j (64-token tile of the wave's quarter): S^T: 4mt x 4rb x 2 = 32 MFMA ->
// exp2 -> pack -> b64 pbuf write; PV: 2ch2 x 4ct x 4rb = 32 MFMA from b128
// pbuf reads + V frags. accO[rb][ct] = O^T [c=ct*16+quad*4+r][q=rb*16+l16].
// Epilogue: lp butterflied over quads; cross-wave denominator = sum of lpx over
// the 4 same-dir waves; 8-phase xbuf merge; wave 0 stores O^T coalesced.
// LDS: pbuf[8][2][4][16][72] = 144KB + lpx 2KB = 146KB <= 160 (1 blk/CU anyway).
// ws: [0,8MB) kt bf16 frag-packed {x1,x2} PRE-SCALED by sqrt(log2(e)/8);
//     [8MB,16MB) vt bf16 frag-packed {x1,x2} unscaled.

#define TT 4096
#define CC 64
#define NB 8

typedef float f32x4 __attribute__((ext_vector_type(4)));
typedef float f32x4a __attribute__((ext_vector_type(4), may_alias));
typedef short s16x8 __attribute__((ext_vector_type(8)));
typedef unsigned int u32x2a __attribute__((ext_vector_type(2), may_alias));
typedef unsigned int u32x4a __attribute__((ext_vector_type(4), may_alias));
typedef float f32a __attribute__((may_alias));

static __device__ __forceinline__ unsigned fbits(float x) { return __float_as_uint(x); }
static __device__ __forceinline__ ushort bf16of(float v) {
    return (ushort)((fbits(v) + 0x8000u) >> 16);
}
static __device__ __forceinline__ unsigned pack2(float a, float b) {
    return __builtin_amdgcn_perm(fbits(b) + 0x8000u, fbits(a) + 0x8000u, 0x07060302u);
}
static __device__ __forceinline__ s16x8 load_frag(const void* p) {
    u32x4a t = *(const u32x4a*)p;
    return __builtin_bit_cast(s16x8, t);
}

#define SQC1 0.4246609177f  // sqrt(log2(e)/8), applied to kt on both Q and K sides

// grid (TT/64, NB, 2), 256 threads. Reads c-major f32, emits frag-packed bf16.
__global__ void prep_k(const float* __restrict__ x1, const float* __restrict__ x2,
                       ushort* __restrict__ kt, ushort* __restrict__ vt) {
    const int inp = blockIdx.z, b = blockIdx.y, tt = blockIdx.x;
    const float* src = (inp == 0 ? x1 : x2) + (size_t)b * CC * TT;
    const size_t plane = (size_t)TT * CC;
    ushort* kd = kt + (size_t)(inp * NB + b) * plane;
    ushort* vd = vt + (size_t)(inp * NB + b) * plane;
    __shared__ ushort lds[64][72];
    const int tid = threadIdx.x;
    const int c  = tid >> 2;        // 0..63: channel row
    const int tg = tid & 3;         // 16-token group within the 64-token tile
    const float* srow = src + (size_t)c * TT + tt * 64 + tg * 16;
    unsigned hw[8];
#pragma unroll
    for (int i = 0; i < 4; ++i) {
        f32x4a v = *(const f32x4a*)(srow + i * 4);
        hw[2 * i]     = pack2(v[0], v[1]);
        hw[2 * i + 1] = pack2(v[2], v[3]);
#pragma unroll
        for (int k = 0; k < 4; ++k) lds[tg * 16 + i * 4 + k][c] = bf16of(v[k] * SQC1);
    }
    // vt frag-packed (unscaled): thread(c,tg) owns V[c][t_local=tg*16..+16] =
    // chunk(tt, ch2=tg>>1, ct=c>>4), lanes (quad=(tg&1)*2 and +1, l16=c&15).
    {
        ushort* vchunk = vd + (((size_t)tt * 2 + (tg >> 1)) * 4 + (c >> 4)) * 512;
        const int l16v = c & 15;
        const int q0v  = (tg & 1) * 2;
        u32x4a w0 = {hw[0], hw[1], hw[2], hw[3]};
        u32x4a w1 = {hw[4], hw[5], hw[6], hw[7]};
        *(u32x4a*)(vchunk + (size_t)(q0v * 16 + l16v) * 8)       = w0;
        *(u32x4a*)(vchunk + (size_t)((q0v + 1) * 16 + l16v) * 8) = w1;
    }
    __syncthreads();
    // kt frag-packed (scaled, from transposed LDS): tid = mt*64 + quad*16 + l16.
    // chunk(tt, mt, ch): lane holds 8 consecutive c at row t = mt*16 + l16.
    const int mt   = tid >> 6;
    const int quad = (tid >> 4) & 3;
    const int l16  = tid & 15;
    const int t    = mt * 16 + l16;
#pragma unroll
    for (int ch = 0; ch < 2; ++ch) {
        u32x4a w = *(const u32x4a*)&lds[t][ch * 32 + quad * 8];
        *(u32x4a*)(kd + (((size_t)tt * 4 + mt) * 2 + ch) * 512 +
                   (size_t)(quad * 16 + l16) * 8) = w;
    }
}

// grid = 512 blocks (qt 0..63 x b 0..7), 512 threads = 8 waves.
// wave: dir = w&1, ksq = w>>1 (1024-token quarter); each wave does all 64 q.
// (512,1): VGPR budget 256 (R28-proved residency-free); demand ~190 fits.
__global__ __launch_bounds__(512, 1)
void attn_fused_k(const ushort* __restrict__ kt, const ushort* __restrict__ vt,
                  float* __restrict__ out) {
    const int b    = blockIdx.x & 7;
    const int qt   = blockIdx.x >> 3;
    const int tid  = threadIdx.x;
    const int wave = tid >> 6;
    const int lane = tid & 63;
    const int quad = lane >> 4;
    const int l16  = lane & 15;
    const int dir  = wave & 1;
    const int ksq  = wave >> 1;      // 0..3: token quarter, 16 j-tiles each

    const size_t plane = (size_t)TT * CC;
    // All hot-loop loads: base + chunk*512 + lane*8 (ushorts) = contiguous 1KB/instr.
    const ushort* Qp = kt + (size_t)((dir == 0 ? 0 : NB) + b) * plane + (size_t)lane * 8;
    const ushort* Kp = kt + (size_t)((dir == 0 ? NB : 0) + b) * plane + (size_t)lane * 8;
    const ushort* Vp = vt + (size_t)((dir == 0 ? NB : 0) + b) * plane + (size_t)lane * 8;

    // Parity pbuf: S(j+1) writes and PV(j) reads touch different regions.
    __shared__ __align__(16) ushort pbuf[8][2][4][16][72];  // 144 KB
    __shared__ float lpx[8][4][16];                         // 2 KB
    f32a* xbuf = (f32a*)&pbuf[0][0][0][0][0];               // 16 KB overlay, post-loop

    // Q b-frags: qf[rb][ch] = kt chunk (qt, mt=rb, ch); q row = rb*16+l16.
    s16x8 qf[4][2];
#pragma unroll
    for (int rb = 0; rb < 4; ++rb)
#pragma unroll
        for (int ch = 0; ch < 2; ++ch)
            qf[rb][ch] = load_frag(Qp + (((size_t)qt * 4 + rb) * 2 + ch) * 512);

    f32x4 accO[4][4];  // O^T partial: row=c=ct*16+quad*4+r, col=q=rb*16+l16
#pragma unroll
    for (int rb = 0; rb < 4; ++rb)
#pragma unroll
        for (int ct = 0; ct < 4; ++ct) accO[rb][ct] = (f32x4){0.f, 0.f, 0.f, 0.f};
    float lp[4] = {0.f, 0.f, 0.f, 0.f};

    // SINGLE named K set + V set (arrays spill — R14/R15).
    s16x8 k0, k1, k2, k3, k4, k5, k6, k7;
    s16x8 v0, v1, v2, v3, v4, v5, v6, v7;

    auto loadK = [&](int j) {
        const ushort* p = Kp + (size_t)(ksq * 16 + j) * 4096;
        k0 = load_frag(p);          k1 = load_frag(p + 512);
        k2 = load_frag(p + 1024);   k3 = load_frag(p + 1536);
        k4 = load_frag(p + 2048);   k5 = load_frag(p + 2560);
        k6 = load_frag(p + 3072);   k7 = load_frag(p + 3584);
    };
    auto loadV = [&](int j) {
        const ushort* p = Vp + (size_t)(ksq * 16 + j) * 4096;
        v0 = load_frag(p);          v1 = load_frag(p + 512);
        v2 = load_frag(p + 1024);   v3 = load_frag(p + 1536);
        v4 = load_frag(p + 2048);   v5 = load_frag(p + 2560);
        v6 = load_frag(p + 3072);   v7 = load_frag(p + 3584);
    };

    // One mt-slice of S^T into parity region par, all 4 rb:
    // D[row=tok=quad*4+r (+mt*16)][col=q=rb*16+l16] -> b64 P write.
    auto SmT = [&](s16x8 kc0, s16x8 kc1, int mt, int par) {
#pragma unroll
        for (int rb = 0; rb < 4; ++rb) {
            f32x4 s = (f32x4){0.f, 0.f, 0.f, 0.f};
            s = __builtin_amdgcn_mfma_f32_16x16x32_bf16(kc0, qf[rb][0], s, 0, 0, 0);
            s = __builtin_amdgcn_mfma_f32_16x16x32_bf16(kc1, qf[rb][1], s, 0, 0, 0);
            float p0 = __builtin_amdgcn_exp2f(s[0]);
            float p1 = __builtin_amdgcn_exp2f(s[1]);
            float p2 = __builtin_amdgcn_exp2f(s[2]);
            float p3 = __builtin_amdgcn_exp2f(s[3]);
            lp[rb] += (p0 + p1) + (p2 + p3);
            u32x2a w;
            w[0] = pack2(p0, p1);
            w[1] = pack2(p2, p3);
            *(u32x2a*)&pbuf[wave][par][rb][l16][mt * 16 + quad * 4] = w;
        }
    };
    auto Sphase = [&](int par) {
        SmT(k0, k1, 0, par); SmT(k2, k3, 1, par);
        SmT(k4, k5, 2, par); SmT(k6, k7, 3, par);
    };

    // PV from parity region par with the V set: 2ch2 x 4ct x 4rb MFMA.
    auto PVphase = [&](int par) {
        s16x8 pfa[4], pfb[4];
#pragma unroll
        for (int rb = 0; rb < 4; ++rb)
            pfa[rb] = load_frag(&pbuf[wave][par][rb][l16][quad * 8]);
#pragma unroll
        for (int rb = 0; rb < 4; ++rb) {
            accO[rb][0] = __builtin_amdgcn_mfma_f32_16x16x32_bf16(v0, pfa[rb], accO[rb][0], 0, 0, 0);
            accO[rb][1] = __builtin_amdgcn_mfma_f32_16x16x32_bf16(v1, pfa[rb], accO[rb][1], 0, 0, 0);
            accO[rb][2] = __builtin_amdgcn_mfma_f32_16x16x32_bf16(v2, pfa[rb], accO[rb][2], 0, 0, 0);
            accO[rb][3] = __builtin_amdgcn_mfma_f32_16x16x32_bf16(v3, pfa[rb], accO[rb][3], 0, 0, 0);
        }
#pragma unroll
        for (int rb = 0; rb < 4; ++rb)
            pfb[rb] = load_frag(&pbuf[wave][par][rb][l16][32 + quad * 8]);
#pragma unroll
        for (int rb = 0; rb < 4; ++rb) {
            accO[rb][0] = __builtin_amdgcn_mfma_f32_16x16x32_bf16(v4, pfb[rb], accO[rb][0], 0, 0, 0);
            accO[rb][1] = __builtin_amdgcn_mfma_f32_16x16x32_bf16(v5, pfb[rb], accO[rb][1], 0, 0, 0);
            accO[rb][2] = __builtin_amdgcn_mfma_f32_16x16x32_bf16(v6, pfb[rb], accO[rb][2], 0, 0, 0);
            accO[rb][3] = __builtin_amdgcn_mfma_f32_16x16x32_bf16(v7, pfb[rb], accO[rb][3], 0, 0, 0);
        }
    };

    // Barrier-free parity pipeline over the wave's 16 tiles, unroll 2.
    // Per iter (j even):
    //   S(j)->par0 | loadK(j+1) | PV(j-1)<-par1 | loadV(j) |
    //   S(j+1)->par1 | loadK(j+2) | PV(j)<-par0 | loadV(j+1)
    // Counted vmcnt waits throughout; every load has >=1 sub-phase of cover.
    loadK(0);
#pragma unroll 1
    for (int j = 0; j < 16; j += 2) {
        Sphase(0);                       // S(j), uses K(j)
        loadK(j + 1);
        if (j > 0) PVphase(1);           // PV(j-1), uses V(j-1)
        loadV(j);
        Sphase(1);                       // S(j+1), uses K(j+1)
        if (j + 2 < 16) loadK(j + 2);
        PVphase(0);                      // PV(j), uses V(j)
        loadV(j + 1);
    }
    PVphase(1);                          // PV(15)

    // Denominator: quads hold disjoint token subsets for col q; butterfly, then
    // sum over the 4 same-dir waves (ksq quarters) via lpx.
#pragma unroll
    for (int rb = 0; rb < 4; ++rb) {
        float l = lp[rb];
        l += __shfl_xor(l, 16);
        l += __shfl_xor(l, 32);
        lp[rb] = l;
        if (lane < 16) lpx[wave][rb][l16] = l;
    }
    __syncthreads();  // joins ALL waves after their last pbuf use ->
                      // xbuf overlay safe; lpx visible
    float inv[4];
#pragma unroll
    for (int rb = 0; rb < 4; ++rb) {
        float l = lpx[dir][rb][l16] + lpx[2 + dir][rb][l16] +
                  lpx[4 + dir][rb][l16] + lpx[6 + dir][rb][l16];
        inv[rb] = __builtin_amdgcn_rcpf(l);
    }

    // 8-phase merge over waves into xbuf (per-dir normalized partials add;
    // outA+outB falls out naturally); wave 0 stores.
#pragma unroll 1
    for (int ph = 7; ph >= 1; --ph) {
        if (wave == ph) {
#pragma unroll
            for (int rb = 0; rb < 4; ++rb)
#pragma unroll
                for (int ct = 0; ct < 4; ++ct)
#pragma unroll
                    for (int r = 0; r < 4; ++r) {
                        const int slot = (rb * 16 + ct * 4 + r) * 64 + lane;
                        float v = accO[rb][ct][r] * inv[rb];
                        if (ph == 7) xbuf[slot] = v;
                        else xbuf[slot] += v;
                    }
        }
        __syncthreads();
    }
    if (wave == 0) {
        float* ob = out + (size_t)b * plane;
#pragma unroll
        for (int rb = 0; rb < 4; ++rb)
#pragma unroll
            for (int ct = 0; ct < 4; ++ct)
#pragma unroll
                for (int r = 0; r < 4; ++r) {
                    float v = accO[rb][ct][r] * inv[rb] +
                              xbuf[(rb * 16 + ct * 4 + r) * 64 + lane];
                    // out[c = ct*16+quad*4+r][t = qt*64 + rb*16 + l16]
                    ob[(size_t)(ct * 16 + quad * 4 + r) * TT + qt * 64 + rb * 16 + l16] = v;
                }
    }
}

extern "C" void kernel_launch(void* const* d_in, const int* in_sizes, int n_in,
                              void* d_out, int out_size, void* d_ws, size_t ws_size,
                              hipStream_t stream) {
    const float* x1 = (const float*)d_in[0];
    const float* x2 = (const float*)d_in[1];
    ushort* kt = (ushort*)d_ws;                              // 8 MB frag-packed K/Q
    ushort* vt = (ushort*)d_ws + (size_t)2 * NB * TT * CC;   // 8 MB frag-packed V

    hipLaunchKernelGGL(prep_k, dim3(TT / 64, NB, 2), dim3(256), 0, stream, x1, x2, kt, vt);
    hipLaunchKernelGGL(attn_fused_k, dim3(64 * NB), dim3(512), 0, stream,
                       kt, vt, (float*)d_out);
}